// Round 12
// baseline (1510.911 us; speedup 1.0000x reference)
//
#include <hip/hip_runtime.h>
#include <hip/hip_bf16.h>
#include <math.h>

#define BB 64      // batch
#define CC 64      // width/channels
#define SS 8192    // sequence
#define HS 4096    // SS/2 (radix-2 half)
#define NMODE 256  // kept rfft modes
#define KK2 512    // 2*NMODE (re/im interleaved, permuted [even-k | odd-k])

typedef __attribute__((ext_vector_type(8))) short short8;
typedef __attribute__((ext_vector_type(16))) float f32x16;

__device__ __forceinline__ float gelu_exact(float v) {
    return 0.5f * v * (1.0f + erff(v * 0.7071067811865476f));
}
__device__ __forceinline__ float b2f(ushort u) {
    return __uint_as_float(((unsigned int)u) << 16);
}
__device__ __forceinline__ ushort f2b(float v) {
    __hip_bfloat16 h = __float2bfloat16(v);  // RNE
    return *(ushort*)&h;
}
__device__ __forceinline__ void split2(float v, ushort& h, ushort& l) {
    h = f2b(v);
    l = f2b(v - b2f(h));
}
// permuted col -> true frequency k
__device__ __forceinline__ int colk(int c) {
    return (c < 256) ? (c & ~1) : (((c - 256) & ~1) | 1);
}

// ---------------- DFT basis tables (bf16 hi/lo pairs, permuted cols) --------
__global__ void build_T1p(ushort* __restrict__ h, ushort* __restrict__ l) {
    int c = blockIdx.x;
    int n = blockIdx.y * 256 + threadIdx.x;
    int k = colk(c), ri = c & 1;
    int m = (n * k) & (SS - 1);
    float th = (float)m * (6.283185307179586476925f / (float)SS);
    float s, co;
    sincosf(th, &s, &co);
    float v = ri ? -s : co;
    ushort hh, ll;
    split2(v, hh, ll);
    h[(size_t)c * HS + n] = hh;
    l[(size_t)c * HS + n] = ll;
}

__global__ void build_T2r(ushort* __restrict__ h, ushort* __restrict__ l) {
    int n = blockIdx.x;
    int c = blockIdx.y * 256 + threadIdx.x;
    int k = colk(c), ri = c & 1;
    int m = (n * k) & (SS - 1);
    float th = (float)m * (6.283185307179586476925f / (float)SS);
    float s, co;
    sincosf(th, &s, &co);
    float v = ri ? -s : co;
    ushort hh, ll;
    split2(v, hh, ll);
    h[(size_t)n * KK2 + c] = hh;
    l[(size_t)n * KK2 + c] = ll;
}

// W1T[j][c] = 0.5 * w1[c][j], split bf16 (head B operand, k-contiguous)
__global__ void build_W1T(const float* __restrict__ w1, ushort* __restrict__ h,
                          ushort* __restrict__ l) {
    int j = blockIdx.x;   // 0..127
    int c = threadIdx.x;  // 0..63
    ushort hh, ll;
    split2(0.5f * w1[c * 128 + j], hh, ll);
    h[j * 64 + c] = hh;
    l[j * 64 + c] = ll;
}

__global__ void zero_xf(float* __restrict__ p) {
    size_t i = ((size_t)blockIdx.x * 256 + threadIdx.x) * 4;
    *(float4*)&p[i] = make_float4(0.f, 0.f, 0.f, 0.f);
}

// ---------------- lifting layer (writes split E/O directly) ----------------
__global__ void lift_kernel(const float* __restrict__ u, const float* __restrict__ w0,
                            const float* __restrict__ b0, ushort* __restrict__ Eh,
                            ushort* __restrict__ El, ushort* __restrict__ Oh,
                            ushort* __restrict__ Ol) {
    int n = blockIdx.x * 256 + threadIdx.x;  // 0..4095
    int c = blockIdx.y;
    int b = blockIdx.z;
    float g1 = (float)n * (1.0f / (float)(SS - 1));
    float g2 = (float)(n + HS) * (1.0f / (float)(SS - 1));
    float v1 = u[b * SS + n] * w0[c] + g1 * w0[CC + c] + b0[c];
    float v2 = u[b * SS + n + HS] * w0[c] + g2 * w0[CC + c] + b0[c];
    float E = v1 + v2, O = v1 - v2;
    ushort hh, ll;
    size_t idx = (size_t)(b * CC + c) * HS + n;
    split2(E, hh, ll);
    Eh[idx] = hh;
    El[idx] = ll;
    split2(O, hh, ll);
    Oh[idx] = hh;
    Ol[idx] = ll;
}

// ---------------- forward truncated DFT (radix-2): K=4096 MFMA GEMM --------
__global__ __launch_bounds__(256, 3) void dft_mfma(
    const ushort* __restrict__ Eh, const ushort* __restrict__ El,
    const ushort* __restrict__ Oh, const ushort* __restrict__ Ol,
    const ushort* __restrict__ t1h, const ushort* __restrict__ t1l,
    float* __restrict__ Xf) {
    __shared__ __align__(16) ushort SM[16384];  // 32 KB
    ushort* As_h = SM;
    ushort* As_l = SM + 4096;
    ushort* Bs_h = SM + 8192;
    ushort* Bs_l = SM + 12288;
    const int t = threadIdx.x;
    const int L = blockIdx.x;  // 512 blocks
    const int gq = L >> 5, j = L & 31;
    const int c0 = (j >> 3) * 128;
    const int m0 = ((gq & 3) * 8 + (j & 7)) * 128;
    const int kz = (gq >> 2) * 1024;  // 4 k-splits over K=4096
    const ushort* __restrict__ Ahp = (c0 < 256) ? Eh : Oh;
    const ushort* __restrict__ Alp = (c0 < 256) ? El : Ol;
    const int lane = t & 63, w = t >> 6;
    const int wm = (w >> 1) * 64, wn = (w & 1) * 64;
    const int l32 = lane & 31, lh = lane >> 5;
    const int sr = t >> 1, sh = (t & 1) * 16;
    const int g0 = (t & 1) * 2;
    const int d0 = ((g0 + 0) * 128 + sr) * 8;
    const int d1 = ((g0 + 1) * 128 + sr) * 8;

    f32x16 acc[2][2];
#pragma unroll
    for (int i = 0; i < 2; i++)
#pragma unroll
        for (int jj = 0; jj < 2; jj++) acc[i][jj] = (f32x16)0.f;

    const size_t arow = (size_t)(m0 + sr) * HS;
    const size_t brow = (size_t)(c0 + sr) * HS;
    const int kend = kz + 1024;

    short8 a0h, a1h, a0l, a1l, b0h, b1h, b0l, b1l;
    {
        const size_t ga = arow + kz + sh;
        const size_t gb = brow + kz + sh;
        a0h = *(const short8*)&Ahp[ga];
        a1h = *(const short8*)&Ahp[ga + 8];
        a0l = *(const short8*)&Alp[ga];
        a1l = *(const short8*)&Alp[ga + 8];
        b0h = *(const short8*)&t1h[gb];
        b1h = *(const short8*)&t1h[gb + 8];
        b0l = *(const short8*)&t1l[gb];
        b1l = *(const short8*)&t1l[gb + 8];
    }
    for (int kt = kz; kt < kend; kt += 32) {
        __syncthreads();
        *(short8*)&As_h[d0] = a0h;
        *(short8*)&As_h[d1] = a1h;
        *(short8*)&As_l[d0] = a0l;
        *(short8*)&As_l[d1] = a1l;
        *(short8*)&Bs_h[d0] = b0h;
        *(short8*)&Bs_h[d1] = b1h;
        *(short8*)&Bs_l[d0] = b0l;
        *(short8*)&Bs_l[d1] = b1l;
        __syncthreads();
        const int ktn = (kt + 32 < kend) ? kt + 32 : kz;
        const size_t ga = arow + ktn + sh;
        const size_t gb = brow + ktn + sh;
        a0h = *(const short8*)&Ahp[ga];
        a1h = *(const short8*)&Ahp[ga + 8];
        a0l = *(const short8*)&Alp[ga];
        a1l = *(const short8*)&Alp[ga + 8];
        b0h = *(const short8*)&t1h[gb];
        b1h = *(const short8*)&t1h[gb + 8];
        b0l = *(const short8*)&t1l[gb];
        b1l = *(const short8*)&t1l[gb + 8];
#pragma unroll
        for (int s2 = 0; s2 < 2; s2++) {
            const int kg = s2 * 2 + lh;
            short8 ah[2], al[2], bh2[2], bl2[2];
#pragma unroll
            for (int mt = 0; mt < 2; mt++) {
                int off = (kg * 128 + wm + mt * 32 + l32) * 8;
                ah[mt] = *(const short8*)&As_h[off];
                al[mt] = *(const short8*)&As_l[off];
            }
#pragma unroll
            for (int nt = 0; nt < 2; nt++) {
                int off = (kg * 128 + wn + nt * 32 + l32) * 8;
                bh2[nt] = *(const short8*)&Bs_h[off];
                bl2[nt] = *(const short8*)&Bs_l[off];
            }
#pragma unroll
            for (int nt = 0; nt < 2; nt++)
#pragma unroll
                for (int mt = 0; mt < 2; mt++) {
                    acc[mt][nt] = __builtin_amdgcn_mfma_f32_32x32x16_bf16(ah[mt], bh2[nt], acc[mt][nt], 0, 0, 0);
                    acc[mt][nt] = __builtin_amdgcn_mfma_f32_32x32x16_bf16(ah[mt], bl2[nt], acc[mt][nt], 0, 0, 0);
                    acc[mt][nt] = __builtin_amdgcn_mfma_f32_32x32x16_bf16(al[mt], bh2[nt], acc[mt][nt], 0, 0, 0);
                }
        }
    }
#pragma unroll
    for (int mt = 0; mt < 2; mt++)
#pragma unroll
        for (int nt = 0; nt < 2; nt++) {
            int col = c0 + wn + nt * 32 + l32;
#pragma unroll
            for (int reg = 0; reg < 16; reg++) {
                int row = m0 + wm + mt * 32 + (reg & 3) + 8 * (reg >> 2) + 4 * lh;
                atomicAdd(&Xf[(size_t)row * KK2 + col], acc[mt][nt][reg]);
            }
        }
}

// ---------------- mode mixing (permuted cols) --------------------------------
__global__ __launch_bounds__(256) void mode_mix(const float* __restrict__ Xf,
                                                const float* __restrict__ swr,
                                                const float* __restrict__ swi,
                                                ushort* __restrict__ omh,
                                                ushort* __restrict__ oml, int l) {
    int k = threadIdx.x;
    int bg = blockIdx.x * 2;
    int og = blockIdx.y * 2;
    const int cp = ((k & 1) << 8) | ((k >> 1) << 1);  // permuted re-col
    float ar[2][2] = {}, ai[2][2] = {};
#pragma unroll 2
    for (int i = 0; i < CC; i++) {
        float2 x0 = *(const float2*)&Xf[((size_t)(bg + 0) * CC + i) * KK2 + cp];
        float2 x1 = *(const float2*)&Xf[((size_t)(bg + 1) * CC + i) * KK2 + cp];
        size_t wb = ((size_t)(l * CC + i) * CC + og) * NMODE + k;
        float wr0 = swr[wb], wi0 = swi[wb];
        float wr1 = swr[wb + NMODE], wi1 = swi[wb + NMODE];
        ar[0][0] += x0.x * wr0 - x0.y * wi0;
        ai[0][0] += x0.x * wi0 + x0.y * wr0;
        ar[0][1] += x0.x * wr1 - x0.y * wi1;
        ai[0][1] += x0.x * wi1 + x0.y * wr1;
        ar[1][0] += x1.x * wr0 - x1.y * wi0;
        ai[1][0] += x1.x * wi0 + x1.y * wr0;
        ar[1][1] += x1.x * wr1 - x1.y * wi1;
        ai[1][1] += x1.x * wi1 + x1.y * wr1;
    }
    float ck = (k == 0) ? (1.0f / (float)SS) : (2.0f / (float)SS);
#pragma unroll
    for (int b2 = 0; b2 < 2; b2++)
#pragma unroll
        for (int oo = 0; oo < 2; oo++) {
            float re = ar[b2][oo] * ck;
            float im = ai[b2][oo] * ck;
            ushort hr, lr2, hi2, li2;
            split2(re, hr, lr2);
            split2(im, hi2, li2);
            size_t base = ((size_t)(bg + b2) * CC + og + oo) * KK2 + cp;
            *(ushort2*)&omh[base] = make_ushort2(hr, hi2);
            *(ushort2*)&oml[base] = make_ushort2(lr2, li2);
        }
}

// ---------------- inverse DFT (radix-2) + pointwise + gelu -------------------
__global__ __launch_bounds__(256, 3) void inv_mfma(
    const ushort* __restrict__ omh, const ushort* __restrict__ oml,
    const ushort* __restrict__ t2h, const ushort* __restrict__ t2l,
    const float* __restrict__ pww, const float* __restrict__ pwb,
    ushort* __restrict__ Eh, ushort* __restrict__ El,
    ushort* __restrict__ Oh, ushort* __restrict__ Ol, int l, int gel) {
    __shared__ __align__(16) ushort SM[12288];  // 24 KB
    ushort* As_h = SM;
    ushort* As_l = SM + 4096;
    ushort* Bs_h = SM + 8192;
    ushort* Bs_l = SM + 10240;
    const int t = threadIdx.x;
    const int n0 = blockIdx.x * 64;    // n < 4096
    const int row0 = blockIdx.y * 128; // 2 batches x 64 out-ch
    const int lane = t & 63, w = t >> 6;
    const int wm = (w >> 1) * 64, wn = (w & 1) * 32;
    const int l32 = lane & 31, lh = lane >> 5;
    const int sr = t >> 1, sh = (t & 1) * 16;
    const int g0 = (t & 1) * 2;
    const int dA0 = ((g0 + 0) * 128 + sr) * 8;
    const int dA1 = ((g0 + 1) * 128 + sr) * 8;
    const int srB = (t >> 1) & 63;
    const int dB0 = ((g0 + 0) * 64 + srB) * 8;
    const int dB1 = ((g0 + 1) * 64 + srB) * 8;
    const bool doB = t < 128;

    f32x16 aP[2], aQ[2];
#pragma unroll
    for (int i = 0; i < 2; i++) {
        aP[i] = (f32x16)0.f;
        aQ[i] = (f32x16)0.f;
    }

    const size_t arow = (size_t)(row0 + sr) * KK2;
    const size_t brow = (size_t)(n0 + srB) * KK2;

    short8 a0h, a1h, a0l, a1l, b0h, b1h, b0l, b1l;
    {
        const size_t ga = arow + sh;
        a0h = *(const short8*)&omh[ga];
        a1h = *(const short8*)&omh[ga + 8];
        a0l = *(const short8*)&oml[ga];
        a1l = *(const short8*)&oml[ga + 8];
        if (doB) {
            const size_t gb = brow + sh;
            b0h = *(const short8*)&t2h[gb];
            b1h = *(const short8*)&t2h[gb + 8];
            b0l = *(const short8*)&t2l[gb];
            b1l = *(const short8*)&t2l[gb + 8];
        }
    }
#pragma unroll
    for (int half = 0; half < 2; half++) {
        f32x16* acc = half ? aQ : aP;
        for (int hs8 = 0; hs8 < 8; hs8++) {
            const int hs = half * 8 + hs8;
            __syncthreads();
            *(short8*)&As_h[dA0] = a0h;
            *(short8*)&As_h[dA1] = a1h;
            *(short8*)&As_l[dA0] = a0l;
            *(short8*)&As_l[dA1] = a1l;
            if (doB) {
                *(short8*)&Bs_h[dB0] = b0h;
                *(short8*)&Bs_h[dB1] = b1h;
                *(short8*)&Bs_l[dB0] = b0l;
                *(short8*)&Bs_l[dB1] = b1l;
            }
            __syncthreads();
            const int ktn = (hs + 1 < 16) ? (hs + 1) * 32 : 0;
            const size_t ga = arow + ktn + sh;
            a0h = *(const short8*)&omh[ga];
            a1h = *(const short8*)&omh[ga + 8];
            a0l = *(const short8*)&oml[ga];
            a1l = *(const short8*)&oml[ga + 8];
            if (doB) {
                const size_t gb = brow + ktn + sh;
                b0h = *(const short8*)&t2h[gb];
                b1h = *(const short8*)&t2h[gb + 8];
                b0l = *(const short8*)&t2l[gb];
                b1l = *(const short8*)&t2l[gb + 8];
            }
#pragma unroll
            for (int s2 = 0; s2 < 2; s2++) {
                const int kg = s2 * 2 + lh;
                short8 ah[2], al[2];
#pragma unroll
                for (int mt = 0; mt < 2; mt++) {
                    int off = (kg * 128 + wm + mt * 32 + l32) * 8;
                    ah[mt] = *(const short8*)&As_h[off];
                    al[mt] = *(const short8*)&As_l[off];
                }
                const int offb = (kg * 64 + wn + l32) * 8;
                short8 bh = *(const short8*)&Bs_h[offb];
                short8 bl = *(const short8*)&Bs_l[offb];
#pragma unroll
                for (int mt = 0; mt < 2; mt++) {
                    acc[mt] = __builtin_amdgcn_mfma_f32_32x32x16_bf16(ah[mt], bh, acc[mt], 0, 0, 0);
                    acc[mt] = __builtin_amdgcn_mfma_f32_32x32x16_bf16(ah[mt], bl, acc[mt], 0, 0, 0);
                    acc[mt] = __builtin_amdgcn_mfma_f32_32x32x16_bf16(al[mt], bh, acc[mt], 0, 0, 0);
                }
            }
        }
    }
#pragma unroll
    for (int mt = 0; mt < 2; mt++) {
        f32x16 p = aP[mt];
        aP[mt] = p + aQ[mt];
        aQ[mt] = p - aQ[mt];
    }
    const int bsw = w >> 1;
    const int xbs = t >> 7, xi = (t >> 1) & 63, xseg = (t & 1) * 32;
    const size_t xg = (size_t)(row0 + xbs * 64 + xi) * HS + n0 + xseg;
    const ushort* const srcs[4] = {Eh, El, Oh, Ol};
#pragma unroll
    for (int r = 0; r < 4; r++) {
        const ushort* src = srcs[r];
        const bool isO = (r >= 2), isHi = !(r & 1);
        short8 v0 = *(const short8*)&src[xg];
        short8 v1 = *(const short8*)&src[xg + 8];
        short8 v2 = *(const short8*)&src[xg + 16];
        short8 v3 = *(const short8*)&src[xg + 24];
        __syncthreads();
        {
            ushort* d = &SM[xbs * 4608 + xi * 72 + xseg];
            *(short8*)d = v0;
            *(short8*)(d + 8) = v1;
            *(short8*)(d + 16) = v2;
            *(short8*)(d + 24) = v3;
        }
        __syncthreads();
#pragma unroll
        for (int ks = 0; ks < 4; ks++) {
            short8 pah[2], pal[2], pnh[2], pnl[2];
#pragma unroll
            for (int mt = 0; mt < 2; mt++) {
                int o = mt * 32 + l32;
                const float* pp = &pww[(size_t)(l * CC + o) * CC + ks * 16 + lh * 8];
                float4 pa = *(const float4*)pp;
                float4 pb = *(const float4*)(pp + 4);
                float pv[8] = {pa.x, pa.y, pa.z, pa.w, pb.x, pb.y, pb.z, pb.w};
#pragma unroll
                for (int e = 0; e < 8; e++) {
                    ushort h2, l2;
                    split2(0.5f * pv[e], h2, l2);
                    pah[mt][e] = (short)h2;
                    pal[mt][e] = (short)l2;
                    pnh[mt][e] = (short)(h2 ^ 0x8000);
                    pnl[mt][e] = (short)(l2 ^ 0x8000);
                }
            }
            short8 bf;
            const int rb = bsw * 4608 + (ks * 16 + lh * 8) * 72 + wn + l32;
#pragma unroll
            for (int jj = 0; jj < 8; jj++) bf[jj] = (short)SM[rb + jj * 72];
#pragma unroll
            for (int mt = 0; mt < 2; mt++) {
                aP[mt] = __builtin_amdgcn_mfma_f32_32x32x16_bf16(pah[mt], bf, aP[mt], 0, 0, 0);
                aQ[mt] = __builtin_amdgcn_mfma_f32_32x32x16_bf16(isO ? pnh[mt] : pah[mt], bf, aQ[mt], 0, 0, 0);
                if (isHi) {
                    aP[mt] = __builtin_amdgcn_mfma_f32_32x32x16_bf16(pal[mt], bf, aP[mt], 0, 0, 0);
                    aQ[mt] = __builtin_amdgcn_mfma_f32_32x32x16_bf16(isO ? pnl[mt] : pal[mt], bf, aQ[mt], 0, 0, 0);
                }
            }
        }
    }
#pragma unroll
    for (int mt = 0; mt < 2; mt++)
#pragma unroll
        for (int reg = 0; reg < 16; reg++) {
            int roffs = (reg & 3) + 8 * (reg >> 2) + 4 * lh;
            int o = mt * 32 + roffs;
            float bias = pwb[l * CC + o];
            float uu = aP[mt][reg] + bias;
            float vv = aQ[mt][reg] + bias;
            if (gel) {
                uu = gelu_exact(uu);
                vv = gelu_exact(vv);
            }
            float EE = uu + vv, OO = uu - vv;
            ushort h2, l2;
            size_t gg = (size_t)(row0 + wm + mt * 32 + roffs) * HS + n0 + wn + l32;
            split2(EE, h2, l2);
            Eh[gg] = h2;
            El[gg] = l2;
            split2(OO, h2, l2);
            Oh[gg] = h2;
            Ol[gg] = l2;
        }
}

// ---------------- projection head (MFMA fc1 with fused E/O butterfly) -------
// Per block: 1 batch x 64 n (n<4096). hE = E*(W1/2), hO = O*(W1/2) as two
// split-bf16 GEMMs (M=64, K=64, N=128); h(n)=hE+hO, h(n+HS)=hE-hO; bias,
// gelu, dot w2 via cross-lane reduction; write both halves.
__global__ __launch_bounds__(256) void head_kernel(
    const ushort* __restrict__ Eh, const ushort* __restrict__ El,
    const ushort* __restrict__ Oh, const ushort* __restrict__ Ol,
    const ushort* __restrict__ w1th, const ushort* __restrict__ w1tl,
    const float* __restrict__ b1, const float* __restrict__ w2,
    const float* __restrict__ b2, float* __restrict__ out) {
    __shared__ __align__(16) ushort SM[18432];  // 4 x [64 n][72] transposed tiles
    ushort* EhT = SM;
    ushort* ElT = SM + 4608;
    ushort* OhT = SM + 9216;
    ushort* OlT = SM + 13824;
    __shared__ float Ru[4][64], Rv[4][64];
    const int b = blockIdx.y;
    const int n0 = blockIdx.x * 64;
    const int t = threadIdx.x;
    const int lane = t & 63, w = t >> 6;
    const int l32 = lane & 31, lh = lane >> 5;
    // ---- stage E/O hi/lo tiles transposed: LDS[n][c], pad 72
    {
        const int c = t >> 2, ns = (t & 3) * 16;
        const size_t g = (size_t)(b * CC + c) * HS + n0 + ns;
        const ushort* const srcs[4] = {Eh, El, Oh, Ol};
        ushort* const dsts[4] = {EhT, ElT, OhT, OlT};
#pragma unroll
        for (int r = 0; r < 4; r++) {
            short8 v0 = *(const short8*)&srcs[r][g];
            short8 v1 = *(const short8*)&srcs[r][g + 8];
            ushort* d = dsts[r];
#pragma unroll
            for (int e = 0; e < 8; e++) {
                d[(ns + e) * 72 + c] = (ushort)v0[e];
                d[(ns + 8 + e) * 72 + c] = (ushort)v1[e];
            }
        }
    }
    // ---- B fragments: W1T (pre-split, 0.5 folded), k-contiguous from global
    const int jbase = w * 32;
    short8 Bh[4], Bl[4];
#pragma unroll
    for (int ks = 0; ks < 4; ks++) {
        const size_t gw = (size_t)(jbase + l32) * 64 + ks * 16 + lh * 8;
        Bh[ks] = *(const short8*)&w1th[gw];
        Bl[ks] = *(const short8*)&w1tl[gw];
    }
    __syncthreads();
    // ---- GEMMs: aE = E^T * W1T, aO = O^T * W1T  (M=64 -> 2 m-tiles)
    f32x16 aE[2], aO[2];
#pragma unroll
    for (int i = 0; i < 2; i++) {
        aE[i] = (f32x16)0.f;
        aO[i] = (f32x16)0.f;
    }
#pragma unroll
    for (int ks = 0; ks < 4; ks++) {
#pragma unroll
        for (int mt = 0; mt < 2; mt++) {
            const int r = (mt * 32 + l32) * 72 + ks * 16 + lh * 8;
            short8 Ah = *(const short8*)&EhT[r];
            short8 Al = *(const short8*)&ElT[r];
            aE[mt] = __builtin_amdgcn_mfma_f32_32x32x16_bf16(Ah, Bh[ks], aE[mt], 0, 0, 0);
            aE[mt] = __builtin_amdgcn_mfma_f32_32x32x16_bf16(Ah, Bl[ks], aE[mt], 0, 0, 0);
            aE[mt] = __builtin_amdgcn_mfma_f32_32x32x16_bf16(Al, Bh[ks], aE[mt], 0, 0, 0);
            Ah = *(const short8*)&OhT[r];
            Al = *(const short8*)&OlT[r];
            aO[mt] = __builtin_amdgcn_mfma_f32_32x32x16_bf16(Ah, Bh[ks], aO[mt], 0, 0, 0);
            aO[mt] = __builtin_amdgcn_mfma_f32_32x32x16_bf16(Ah, Bl[ks], aO[mt], 0, 0, 0);
            aO[mt] = __builtin_amdgcn_mfma_f32_32x32x16_bf16(Al, Bh[ks], aO[mt], 0, 0, 0);
        }
    }
    // ---- epilogue: butterfly, bias, gelu, dot w2, cross-lane reduce
    // C layout: col(j) = jbase + l32; row = mt*32 + (reg&3)+8*(reg>>2)+4*lh
    const float b1v = b1[jbase + l32];
    const float w2v = w2[jbase + l32];
    float pu[32], pv[32];  // indexed mt*16+reg
#pragma unroll
    for (int mt = 0; mt < 2; mt++)
#pragma unroll
        for (int reg = 0; reg < 16; reg++) {
            float hu = aE[mt][reg] + aO[mt][reg] + b1v;
            float hv = aE[mt][reg] - aO[mt][reg] + b1v;
            pu[mt * 16 + reg] = gelu_exact(hu) * w2v;
            pv[mt * 16 + reg] = gelu_exact(hv) * w2v;
        }
#pragma unroll
    for (int m = 1; m <= 16; m <<= 1)
#pragma unroll
        for (int i = 0; i < 32; i++) {
            pu[i] += __shfl_xor(pu[i], m, 64);
            pv[i] += __shfl_xor(pv[i], m, 64);
        }
    if (l32 == 0) {
#pragma unroll
        for (int mt = 0; mt < 2; mt++)
#pragma unroll
            for (int reg = 0; reg < 16; reg++) {
                int row = mt * 32 + (reg & 3) + 8 * (reg >> 2) + 4 * lh;
                Ru[w][row] = pu[mt * 16 + reg];
                Rv[w][row] = pv[mt * 16 + reg];
            }
    }
    __syncthreads();
    if (t < 64) {
        float su = Ru[0][t] + Ru[1][t] + Ru[2][t] + Ru[3][t] + b2[0];
        float sv = Rv[0][t] + Rv[1][t] + Rv[2][t] + Rv[3][t] + b2[0];
        out[(size_t)b * SS + n0 + t] = su;
        out[(size_t)b * SS + n0 + t + HS] = sv;
    }
}

extern "C" void kernel_launch(void* const* d_in, const int* in_sizes, int n_in,
                              void* d_out, int out_size, void* d_ws, size_t ws_size,
                              hipStream_t stream) {
    (void)in_sizes; (void)n_in; (void)out_size; (void)ws_size;
    const float* u = (const float*)d_in[0];
    const float* fc0_w = (const float*)d_in[1];
    const float* fc0_b = (const float*)d_in[2];
    const float* sw_r = (const float*)d_in[3];
    const float* sw_i = (const float*)d_in[4];
    const float* pw_w = (const float*)d_in[5];
    const float* pw_b = (const float*)d_in[6];
    const float* fc1_w = (const float*)d_in[7];
    const float* fc1_b = (const float*)d_in[8];
    const float* fc2_w = (const float*)d_in[9];
    const float* fc2_b = (const float*)d_in[10];
    float* out = (float*)d_out;

    // workspace layout (total = 167,804,928 B)
    char* ws = (char*)d_ws;
    ushort* Eh = (ushort*)ws;                  // [4096][4096]
    ushort* El = (ushort*)(ws + 33554432);
    ushort* Oh = (ushort*)(ws + 67108864);
    ushort* Ol = (ushort*)(ws + 100663296);
    ushort* t1h = (ushort*)(ws + 134217728);   // [512][4096]
    ushort* t1l = (ushort*)(ws + 138412032);
    ushort* t2h = (ushort*)(ws + 142606336);   // [4096][512]
    ushort* t2l = (ushort*)(ws + 146800640);
    ushort* omh = (ushort*)(ws + 150994944);   // [4096][512]
    ushort* oml = (ushort*)(ws + 155189248);
    float* Xf = (float*)(ws + 159383552);      // [4096][512] fp32
    ushort* w1th = (ushort*)(ws + 167772160);  // [128][64] split W1^T/2
    ushort* w1tl = (ushort*)(ws + 167788544);

    build_T1p<<<dim3(KK2, HS / 256), 256, 0, stream>>>(t1h, t1l);
    build_T2r<<<dim3(HS, KK2 / 256), 256, 0, stream>>>(t2h, t2l);
    build_W1T<<<dim3(128), 64, 0, stream>>>(fc1_w, w1th, w1tl);
    lift_kernel<<<dim3(HS / 256, CC, BB), 256, 0, stream>>>(u, fc0_w, fc0_b, Eh, El,
                                                            Oh, Ol);
    for (int l = 0; l < 4; l++) {
        zero_xf<<<dim3(2048), 256, 0, stream>>>(Xf);
        dft_mfma<<<dim3(512), 256, 0, stream>>>(Eh, El, Oh, Ol, t1h, t1l, Xf);
        mode_mix<<<dim3(BB / 2, CC / 2), 256, 0, stream>>>(Xf, sw_r, sw_i, omh, oml, l);
        inv_mfma<<<dim3(HS / 64, 32), 256, 0, stream>>>(
            omh, oml, t2h, t2l, pw_w, pw_b, Eh, El, Oh, Ol, l, (l < 3) ? 1 : 0);
    }
    head_kernel<<<dim3(HS / 64, BB), 256, 0, stream>>>(Eh, El, Oh, Ol, w1th, w1tl,
                                                       fc1_b, fc2_w, fc2_b, out);
}